// Round 13
// baseline (90.678 us; speedup 1.0000x reference)
//
#include <hip/hip_runtime.h>

// PointWarping2: Nadaraya-Watson regression of flow1 (at warped sources
// y = xyz1+flow1) onto queries xyz2. B=2,C=3,N1=N2=8192 fp32.
//
// R13: async LDS pipeline via __builtin_amdgcn_global_load_lds (width 16).
// R8-R12 evidence: register-stream loads stall every iteration (load result
// consumed into the ring register same-iteration -> waitcnt ~118cyc after
// issue < ~200cyc L2 latency). The DMA path has no VGPR destination; with a
// 4-slot LDS ring and stage(t+3) issued BEFORE compute(t), the barrier's
// vmcnt drain waits on a ~470cyc-old load -> stalls gone (m97 pattern).
// 1024 blocks x 256 thr; block = 16 queries x 8192 sources; wave (g,h) =
// query octet g, source half h; all 4 waves stage a quarter tile each.
// Kept: 16B packed records (fp16 y, bf16 f, fp32 magic-folded yc),
// f2 pk math, Schraudolph exp2 (absmax 0.0586), SGPR query consts,
// split-exchange butterfly reduction.

#define N1S  8192
#define N2S  8192
#define BATCH 2
#define NS   (BATCH * N1S)     // 16384 sources
#define NQ   (BATCH * N2S)     // 16384 queries
#define BLK  256               // 4 waves
#define QB   16                // queries per block (2 octets)
#define QP   4                 // f2 query-pairs per wave (8 queries)
#define TS   256               // sources per tile
#define NTILE (N1S / TS)       // 32
#define LOG2E 1.4426950408889634f
#define MAGIC 49152.0f         // 1.5*2^15
#define CLAMPS (MAGIC - 120.0f)
#define KBITS 1064990910       // (127<<23) - 362306: rel err +-3.04%

typedef float f2 __attribute__((ext_vector_type(2)));
typedef const __attribute__((address_space(1))) void gvoid;   // global
typedef __attribute__((address_space(3))) void svoid;         // LDS

__device__ __forceinline__ f2 fma2(f2 a, f2 b, f2 c) {
    return __builtin_elementwise_fma(a, b, c);
}
__device__ __forceinline__ f2 max2(f2 a, f2 b) {
    return __builtin_elementwise_max(a, b);
}

__device__ __forceinline__ float rfl(float x) {   // force wave-uniform -> SGPR
    return __builtin_bit_cast(float,
        __builtin_amdgcn_readfirstlane(__builtin_bit_cast(int, x)));
}

__device__ __forceinline__ float read_scale(const void* p) {
    // resol_factor: 1-elem array; Python int -> int32, float -> fp32.
    int iv = *(const int*)p;
    if (iv > -(1 << 23) && iv < (1 << 23)) return (float)iv;
    return *(const float*)p;
}

__device__ __forceinline__ unsigned bf16_rne(float v) {   // round-nearest-even
    unsigned u = __builtin_bit_cast(unsigned, v);
    return (u + 0x7FFFu + ((u >> 16) & 1u)) >> 16;
}
__device__ __forceinline__ unsigned h16(float v) {        // fp16 bits
    return (unsigned)__builtin_bit_cast(unsigned short, (_Float16)v);
}
__device__ __forceinline__ float h2f(unsigned bits16) {   // fp16 bits -> fp32
    return (float)__builtin_bit_cast(_Float16, (unsigned short)bits16);
}

// ---- k1: pack one uint4 record per source ----
__global__ __launch_bounds__(256) void pw2_pack(
    const float* __restrict__ xyz1, const float* __restrict__ flow1,
    const void* __restrict__ resol, uint4* __restrict__ src)
{
    int i = blockIdx.x * 256 + threadIdx.x;
    if (i >= NS) return;
    int b = i >> 13, m = i & (N1S - 1);
    const float scale = read_scale(resol);
    const float c1 = LOG2E / (scale * scale);
    const float* x1b = xyz1  + b * 3 * N1S;
    const float* f1b = flow1 + b * 3 * N1S;
    float fx = f1b[0*N1S+m], fy = f1b[1*N1S+m], fz = f1b[2*N1S+m];
    float yx = x1b[0*N1S+m]+fx, yy = x1b[1*N1S+m]+fy, yz = x1b[2*N1S+m]+fz;
    float yc = MAGIC - c1 * (yx*yx + yy*yy + yz*yz);  // fp32: exact fold
    uint4 u;
    u.x = (h16(yy) << 16) | h16(yx);
    u.y = (bf16_rne(fx) << 16) | h16(yz);
    u.z = (bf16_rne(fz) << 16) | bf16_rne(fy);
    u.w = __builtin_bit_cast(unsigned, yc);
    src[i] = u;
}

// ---- k2: main kernel, async-LDS pipelined ----
__global__ __launch_bounds__(BLK) void pw2_main(
    const uint4* __restrict__ src, const float* __restrict__ xyz2,
    const void* __restrict__ resol, float* __restrict__ out)
{
    __shared__ uint4 ring[4][TS];      // 16 KB, 4-slot tile ring
    __shared__ float red[4 * 32];      // [wave][32 reduced values]

    const int t = threadIdx.x;
    const int w = t >> 6;              // wave 0..3
    const int l = t & 63;
    const int g = w >> 1;              // query octet (0/1)
    const int h = w & 1;               // source half (0/1)

    const int b     = blockIdx.x >> 9;             // 512 blocks per batch
    const int nbase = (blockIdx.x & 511) * QB;

    const float scale = read_scale(resol);   // INITIAL_RADIUS == 1.0
    const float c1    = LOG2E / (scale * scale);
    const float twoC  = 2.0f * c1;

    const float* x2b  = xyz2 + b * 3 * N2S;
    const uint4* srcb = src + b * N1S;

    // ---- wave-uniform query constants (8 queries, f2 pairs) -> SGPRs ----
    f2 qx[QP], qy[QP], qz[QP], qc[QP];
#pragma unroll
    for (int jp = 0; jp < QP; ++jp) {
        int n0 = nbase + g * 8 + 2 * jp;
        float x0 = x2b[0*N2S+n0],   y0 = x2b[1*N2S+n0],   z0 = x2b[2*N2S+n0];
        float x1 = x2b[0*N2S+n0+1], y1 = x2b[1*N2S+n0+1], z1 = x2b[2*N2S+n0+1];
        qc[jp] = (f2){rfl(-c1 * (x0*x0 + y0*y0 + z0*z0)),
                      rfl(-c1 * (x1*x1 + y1*y1 + z1*z1))};
        qx[jp] = (f2){rfl(twoC*x0), rfl(twoC*x1)};
        qy[jp] = (f2){rfl(twoC*y0), rfl(twoC*y1)};
        qz[jp] = (f2){rfl(twoC*z0), rfl(twoC*z1)};
    }
    const f2 clamp2 = (f2){CLAMPS, CLAMPS};

    // acc.v2[c*QP+jp]: c=0/1/2 numerator xyz, c=3 denominator; 32 floats
    union Acc { f2 v2[16]; float v1[32]; } acc;
#pragma unroll
    for (int i = 0; i < 16; ++i) acc.v2[i] = (f2){0.f, 0.f};

// wave w DMA-stages quarter w of tile TT into ring slot TT&3 (1 KB/wave)
#define STAGE(TT) do {                                                        \
    const uint4* gp = srcb + (TT) * TS + (w << 6) + l;                        \
    __builtin_amdgcn_global_load_lds((gvoid*)gp,                              \
        (svoid*)&ring[(TT) & 3][w << 6], 16, 0, 0);                           \
} while (0)

#define BODY(U) do {                                                          \
    float vyx = h2f((U).x & 0xFFFFu);                                         \
    float vyy = h2f((U).x >> 16);                                             \
    float vyz = h2f((U).y & 0xFFFFu);                                         \
    float ffx = __builtin_bit_cast(float, (U).y & 0xFFFF0000u);               \
    float ffy = __builtin_bit_cast(float, (U).z << 16);                       \
    float ffz = __builtin_bit_cast(float, (U).z & 0xFFFF0000u);               \
    float vyc = __builtin_bit_cast(float, (U).w);                             \
    f2 yaw = (f2){vyc, vyc};                                                  \
    f2 yax = (f2){vyx, vyx}, yay = (f2){vyy, vyy}, yaz = (f2){vyz, vyz};      \
    f2 fax = (f2){ffx, ffx}, fay = (f2){ffy, ffy}, faz = (f2){ffz, ffz};      \
    _Pragma("unroll")                                                         \
    for (int jp = 0; jp < QP; ++jp) {                                         \
        f2 arg = qc[jp] + yaw;                                                \
        arg = fma2(qx[jp], yax, arg);                                         \
        arg = fma2(qy[jp], yay, arg);                                         \
        arg = fma2(qz[jp], yaz, arg);                                         \
        f2 s = max2(arg, clamp2);                                             \
        f2 wgt = (f2){                                                        \
            __builtin_bit_cast(float,                                         \
                (__builtin_bit_cast(int, s.x) << 15) + KBITS),                \
            __builtin_bit_cast(float,                                         \
                (__builtin_bit_cast(int, s.y) << 15) + KBITS)};               \
        acc.v2[0*QP+jp] = fma2(wgt, fax, acc.v2[0*QP+jp]);                    \
        acc.v2[1*QP+jp] = fma2(wgt, fay, acc.v2[1*QP+jp]);                    \
        acc.v2[2*QP+jp] = fma2(wgt, faz, acc.v2[2*QP+jp]);                    \
        acc.v2[3*QP+jp] = acc.v2[3*QP+jp] + wgt;                              \
    }                                                                         \
} while (0)

    // ---- prologue: stage tiles 0..2, one drain ----
    STAGE(0); STAGE(1); STAGE(2);
    __syncthreads();

    // ---- K-loop: issue stage(t+3) BEFORE compute(t); barrier drains a
    //      ~470-cycle-old DMA (m97 ordering) ----
    for (int tt = 0; tt < NTILE; ++tt) {
        if (tt + 3 < NTILE) STAGE(tt + 3);
#pragma unroll
        for (int k = 0; k < 2; ++k) {
            uint4 U = ring[tt & 3][h * 128 + k * 64 + l];
            BODY(U);
        }
        __syncthreads();   // emits s_waitcnt vmcnt(0) + s_barrier
    }
#undef BODY
#undef STAGE

    // ---- split-exchange butterfly: 32 values, offsets 1..16 ----
#pragma unroll
    for (int step = 0; step < 5; ++step) {
        const int off  = 1 << step;
        const int half = 16 >> step;
        const bool hi  = (l & off) != 0;
#pragma unroll
        for (int k = 0; k < half; ++k) {
            float give = hi ? acc.v1[k] : acc.v1[k + half];
            float recv = __shfl_xor(give, off, 64);
            float keep = hi ? acc.v1[k + half] : acc.v1[k];
            acc.v1[k] = keep + recv;
        }
    }
    acc.v1[0] += __shfl_xor(acc.v1[0], 32, 64);  // merge the two 32-lane halves
    if (l < 32) red[w * 32 + (__brev((unsigned)l) >> 27)] = acc.v1[0];
    __syncthreads();

    // ---- combine the two source-halves per query octet, write ----
    if (t < QB) {
        int j = t & 7;
        const float* r0 = red + (t >> 3) * 64;        // waves 2g, 2g+1
        const float* r1 = r0 + 32;
        // flat value index for component c of query j: 2*(c*QP + j/2) + (j&1)
        float nx = r0[2*(0*QP+(j>>1))+(j&1)] + r1[2*(0*QP+(j>>1))+(j&1)];
        float ny = r0[2*(1*QP+(j>>1))+(j&1)] + r1[2*(1*QP+(j>>1))+(j&1)];
        float nz = r0[2*(2*QP+(j>>1))+(j&1)] + r1[2*(2*QP+(j>>1))+(j&1)];
        float dn = r0[2*(3*QP+(j>>1))+(j&1)] + r1[2*(3*QP+(j>>1))+(j&1)];
        float inv = 1.0f / dn;
        int n = nbase + t;
        out[b*3*N2S + 0*N2S + n] = x2b[0*N2S+n] - nx*inv;
        out[b*3*N2S + 1*N2S + n] = x2b[1*N2S+n] - ny*inv;
        out[b*3*N2S + 2*N2S + n] = x2b[2*N2S+n] - nz*inv;
    }
}

extern "C" void kernel_launch(void* const* d_in, const int* in_sizes, int n_in,
                              void* d_out, int out_size, void* d_ws, size_t ws_size,
                              hipStream_t stream) {
    const float* xyz1  = (const float*)d_in[0];
    const float* xyz2  = (const float*)d_in[1];
    const float* flow1 = (const float*)d_in[2];
    const void*  resol = d_in[3];
    float* out = (float*)d_out;

    uint4* src = (uint4*)d_ws;             // NS uint4 = 256 KB

    pw2_pack<<<NS / 256, 256, 0, stream>>>(xyz1, flow1, resol, src);
    pw2_main<<<NQ / QB, BLK, 0, stream>>>(src, xyz2, resol, out);
}

// Round 14
// 89.737 us; speedup vs baseline: 1.0105x; 1.0105x over previous
//
#include <hip/hip_runtime.h>

// PointWarping2: Nadaraya-Watson regression of flow1 (at warped sources
// y = xyz1+flow1) onto queries xyz2. B=2,C=3,N1=N2=8192 fp32.
//
// R14 = R13's async-LDS DMA ring at 2x wave residency, half the barriers.
// R7-R13 post-mortem: kernel is VALU-FLOP-bound while busy (~80% of busy
// cycles are the irreducible ~10 ops/pair; pk gains nothing - gfx950 fp32
// peak is plain-FMA rate) but idles ~40% of wall time at 4 waves/SIMD with
// 32 full-drain barriers. Fix residency, not bytes:
//   BLK=512 (8 waves), TS=512 (8KB tile = 1 global_load_lds dwordx4 per
//   wave per tile), NTILE=16, 4-slot ring (32KB), 2 blocks/CU ->
//   8 waves/SIMD, 16 barriers, traffic unchanged (134 MB).
// Wave (g=w>>2, s=w&3): query octet g, source quarter s (32 BODYs/wave).
// Kept: 16B packed records (fp16 y, bf16 f, fp32 magic-folded yc),
// Schraudolph exp2 (absmax 0.0586 < 0.0862), SGPR query consts,
// split-exchange butterfly reduction.

#define N1S  8192
#define N2S  8192
#define BATCH 2
#define NS   (BATCH * N1S)     // 16384 sources
#define NQ   (BATCH * N2S)     // 16384 queries
#define BLK  512               // 8 waves
#define QB   16                // queries per block (2 octets)
#define QP   4                 // f2 query-pairs per wave (8 queries)
#define TS   512               // sources per tile (8 KB)
#define NTILE (N1S / TS)       // 16
#define LOG2E 1.4426950408889634f
#define MAGIC 49152.0f         // 1.5*2^15
#define CLAMPS (MAGIC - 120.0f)
#define KBITS 1064990910       // (127<<23) - 362306: rel err +-3.04%

typedef float f2 __attribute__((ext_vector_type(2)));
typedef const __attribute__((address_space(1))) void gvoid;   // global
typedef __attribute__((address_space(3))) void svoid;         // LDS

__device__ __forceinline__ f2 fma2(f2 a, f2 b, f2 c) {
    return __builtin_elementwise_fma(a, b, c);
}
__device__ __forceinline__ f2 max2(f2 a, f2 b) {
    return __builtin_elementwise_max(a, b);
}

__device__ __forceinline__ float rfl(float x) {   // force wave-uniform -> SGPR
    return __builtin_bit_cast(float,
        __builtin_amdgcn_readfirstlane(__builtin_bit_cast(int, x)));
}

__device__ __forceinline__ float read_scale(const void* p) {
    // resol_factor: 1-elem array; Python int -> int32, float -> fp32.
    int iv = *(const int*)p;
    if (iv > -(1 << 23) && iv < (1 << 23)) return (float)iv;
    return *(const float*)p;
}

__device__ __forceinline__ unsigned bf16_rne(float v) {   // round-nearest-even
    unsigned u = __builtin_bit_cast(unsigned, v);
    return (u + 0x7FFFu + ((u >> 16) & 1u)) >> 16;
}
__device__ __forceinline__ unsigned h16(float v) {        // fp16 bits
    return (unsigned)__builtin_bit_cast(unsigned short, (_Float16)v);
}
__device__ __forceinline__ float h2f(unsigned bits16) {   // fp16 bits -> fp32
    return (float)__builtin_bit_cast(_Float16, (unsigned short)bits16);
}

// ---- k1: pack one uint4 record per source ----
__global__ __launch_bounds__(256) void pw2_pack(
    const float* __restrict__ xyz1, const float* __restrict__ flow1,
    const void* __restrict__ resol, uint4* __restrict__ src)
{
    int i = blockIdx.x * 256 + threadIdx.x;
    if (i >= NS) return;
    int b = i >> 13, m = i & (N1S - 1);
    const float scale = read_scale(resol);
    const float c1 = LOG2E / (scale * scale);
    const float* x1b = xyz1  + b * 3 * N1S;
    const float* f1b = flow1 + b * 3 * N1S;
    float fx = f1b[0*N1S+m], fy = f1b[1*N1S+m], fz = f1b[2*N1S+m];
    float yx = x1b[0*N1S+m]+fx, yy = x1b[1*N1S+m]+fy, yz = x1b[2*N1S+m]+fz;
    float yc = MAGIC - c1 * (yx*yx + yy*yy + yz*yz);  // fp32: exact fold
    uint4 u;
    u.x = (h16(yy) << 16) | h16(yx);
    u.y = (bf16_rne(fx) << 16) | h16(yz);
    u.z = (bf16_rne(fz) << 16) | bf16_rne(fy);
    u.w = __builtin_bit_cast(unsigned, yc);
    src[i] = u;
}

// ---- k2: main kernel, async-LDS pipelined, 8 waves/block ----
__global__ __launch_bounds__(BLK) void pw2_main(
    const uint4* __restrict__ src, const float* __restrict__ xyz2,
    const void* __restrict__ resol, float* __restrict__ out)
{
    __shared__ uint4 ring[4][TS];      // 32 KB, 4-slot tile ring
    __shared__ float red[8 * 32];      // [wave][32 reduced values]

    const int t = threadIdx.x;
    const int w = t >> 6;              // wave 0..7
    const int l = t & 63;
    const int g = w >> 2;              // query octet (0/1)
    const int s = w & 3;               // source quarter (0..3)

    const int b     = blockIdx.x >> 9;             // 512 blocks per batch
    const int nbase = (blockIdx.x & 511) * QB;

    const float scale = read_scale(resol);   // INITIAL_RADIUS == 1.0
    const float c1    = LOG2E / (scale * scale);
    const float twoC  = 2.0f * c1;

    const float* x2b  = xyz2 + b * 3 * N2S;
    const uint4* srcb = src + b * N1S;

    // ---- wave-uniform query constants (8 queries, f2 pairs) -> SGPRs ----
    f2 qx[QP], qy[QP], qz[QP], qc[QP];
#pragma unroll
    for (int jp = 0; jp < QP; ++jp) {
        int n0 = nbase + g * 8 + 2 * jp;
        float x0 = x2b[0*N2S+n0],   y0 = x2b[1*N2S+n0],   z0 = x2b[2*N2S+n0];
        float x1 = x2b[0*N2S+n0+1], y1 = x2b[1*N2S+n0+1], z1 = x2b[2*N2S+n0+1];
        qc[jp] = (f2){rfl(-c1 * (x0*x0 + y0*y0 + z0*z0)),
                      rfl(-c1 * (x1*x1 + y1*y1 + z1*z1))};
        qx[jp] = (f2){rfl(twoC*x0), rfl(twoC*x1)};
        qy[jp] = (f2){rfl(twoC*y0), rfl(twoC*y1)};
        qz[jp] = (f2){rfl(twoC*z0), rfl(twoC*z1)};
    }
    const f2 clamp2 = (f2){CLAMPS, CLAMPS};

    // acc.v2[c*QP+jp]: c=0/1/2 numerator xyz, c=3 denominator; 32 floats
    union Acc { f2 v2[16]; float v1[32]; } acc;
#pragma unroll
    for (int i = 0; i < 16; ++i) acc.v2[i] = (f2){0.f, 0.f};

// wave w DMA-stages eighth w of tile TT into ring slot TT&3 (1 KB/wave)
#define STAGE(TT) do {                                                        \
    const uint4* gp = srcb + (TT) * TS + (w << 6) + l;                        \
    __builtin_amdgcn_global_load_lds((gvoid*)gp,                              \
        (svoid*)&ring[(TT) & 3][w << 6], 16, 0, 0);                           \
} while (0)

#define BODY(U) do {                                                          \
    float vyx = h2f((U).x & 0xFFFFu);                                         \
    float vyy = h2f((U).x >> 16);                                             \
    float vyz = h2f((U).y & 0xFFFFu);                                         \
    float ffx = __builtin_bit_cast(float, (U).y & 0xFFFF0000u);               \
    float ffy = __builtin_bit_cast(float, (U).z << 16);                       \
    float ffz = __builtin_bit_cast(float, (U).z & 0xFFFF0000u);               \
    float vyc = __builtin_bit_cast(float, (U).w);                             \
    f2 yaw = (f2){vyc, vyc};                                                  \
    f2 yax = (f2){vyx, vyx}, yay = (f2){vyy, vyy}, yaz = (f2){vyz, vyz};      \
    f2 fax = (f2){ffx, ffx}, fay = (f2){ffy, ffy}, faz = (f2){ffz, ffz};      \
    _Pragma("unroll")                                                         \
    for (int jp = 0; jp < QP; ++jp) {                                         \
        f2 arg = qc[jp] + yaw;                                                \
        arg = fma2(qx[jp], yax, arg);                                         \
        arg = fma2(qy[jp], yay, arg);                                         \
        arg = fma2(qz[jp], yaz, arg);                                         \
        f2 ss = max2(arg, clamp2);                                            \
        f2 wgt = (f2){                                                        \
            __builtin_bit_cast(float,                                         \
                (__builtin_bit_cast(int, ss.x) << 15) + KBITS),               \
            __builtin_bit_cast(float,                                         \
                (__builtin_bit_cast(int, ss.y) << 15) + KBITS)};              \
        acc.v2[0*QP+jp] = fma2(wgt, fax, acc.v2[0*QP+jp]);                    \
        acc.v2[1*QP+jp] = fma2(wgt, fay, acc.v2[1*QP+jp]);                    \
        acc.v2[2*QP+jp] = fma2(wgt, faz, acc.v2[2*QP+jp]);                    \
        acc.v2[3*QP+jp] = acc.v2[3*QP+jp] + wgt;                              \
    }                                                                         \
} while (0)

    // ---- prologue: stage tiles 0..2, one drain ----
    STAGE(0); STAGE(1); STAGE(2);
    __syncthreads();

    // ---- K-loop: issue stage(t+3) BEFORE compute(t) ----
    for (int tt = 0; tt < NTILE; ++tt) {
        if (tt + 3 < NTILE) STAGE(tt + 3);
#pragma unroll
        for (int k = 0; k < 2; ++k) {    // this wave's source quarter
            uint4 U = ring[tt & 3][s * 128 + k * 64 + l];
            BODY(U);
        }
        __syncthreads();   // emits s_waitcnt vmcnt(0) + s_barrier
    }
#undef BODY
#undef STAGE

    // ---- split-exchange butterfly: 32 values, offsets 1..16 ----
#pragma unroll
    for (int step = 0; step < 5; ++step) {
        const int off  = 1 << step;
        const int half = 16 >> step;
        const bool hi  = (l & off) != 0;
#pragma unroll
        for (int k = 0; k < half; ++k) {
            float give = hi ? acc.v1[k] : acc.v1[k + half];
            float recv = __shfl_xor(give, off, 64);
            float keep = hi ? acc.v1[k + half] : acc.v1[k];
            acc.v1[k] = keep + recv;
        }
    }
    acc.v1[0] += __shfl_xor(acc.v1[0], 32, 64);  // merge the two 32-lane halves
    if (l < 32) red[w * 32 + (__brev((unsigned)l) >> 27)] = acc.v1[0];
    __syncthreads();

    // ---- combine the 4 source-quarter partials per query, write ----
    if (t < QB) {
        int j = t & 7;                    // query within octet
        int oc = t >> 3;                  // octet
        // flat value index for component c of query j: 2*(c*QP + j/2) + (j&1)
        float nx = 0.f, ny = 0.f, nz = 0.f, dn = 0.f;
#pragma unroll
        for (int ww = 0; ww < 4; ++ww) {
            const float* r = red + (oc * 4 + ww) * 32;
            nx += r[2*(0*QP+(j>>1))+(j&1)];
            ny += r[2*(1*QP+(j>>1))+(j&1)];
            nz += r[2*(2*QP+(j>>1))+(j&1)];
            dn += r[2*(3*QP+(j>>1))+(j&1)];
        }
        float inv = 1.0f / dn;
        int n = nbase + t;
        out[b*3*N2S + 0*N2S + n] = x2b[0*N2S+n] - nx*inv;
        out[b*3*N2S + 1*N2S + n] = x2b[1*N2S+n] - ny*inv;
        out[b*3*N2S + 2*N2S + n] = x2b[2*N2S+n] - nz*inv;
    }
}

extern "C" void kernel_launch(void* const* d_in, const int* in_sizes, int n_in,
                              void* d_out, int out_size, void* d_ws, size_t ws_size,
                              hipStream_t stream) {
    const float* xyz1  = (const float*)d_in[0];
    const float* xyz2  = (const float*)d_in[1];
    const float* flow1 = (const float*)d_in[2];
    const void*  resol = d_in[3];
    float* out = (float*)d_out;

    uint4* src = (uint4*)d_ws;             // NS uint4 = 256 KB

    pw2_pack<<<NS / 256, 256, 0, stream>>>(xyz1, flow1, resol, src);
    pw2_main<<<NQ / QB, BLK, 0, stream>>>(src, xyz2, resol, out);
}